// Round 3
// baseline (480.219 us; speedup 1.0000x reference)
//
#include <hip/hip_runtime.h>

typedef __attribute__((ext_vector_type(8))) short short8;
typedef __attribute__((ext_vector_type(4))) float f32x4;

#define L2E 1.44269504088896340736f

__device__ __forceinline__ unsigned short f2bf(float x) {
    union { float f; unsigned int u; } v; v.f = x;
    unsigned int u = v.u;
    unsigned int r = (u + 0x7FFFu + ((u >> 16) & 1u)) >> 16;
    return (unsigned short)r;
}

__device__ __forceinline__ float mishf(float x) {
    float u = __builtin_amdgcn_exp2f(x * L2E);
    float t = u * (u + 2.0f);
    return x * t * __builtin_amdgcn_rcpf(t + 2.0f);
}

// masked p = adj_bit * exp(mish(s1+s2)) in bf16; s1v/sv pre-scaled by log2(e).
__device__ __forceinline__ short pw(unsigned int mb, int j, float sv, float s1v) {
    float xL = s1v + sv;
    float u = __builtin_amdgcn_exp2f(xL);
    float t = u * (u + 2.0f);
    float m = xL * t * __builtin_amdgcn_rcpf(t + 2.0f);
    float p = __builtin_amdgcn_exp2f(m);
    union { float f; unsigned int u; } b; b.f = p;
    unsigned short h = (unsigned short)((b.u + 0x8000u) >> 16);
    return ((mb >> j) & 1u) ? (short)h : (short)0;
}

typedef __attribute__((address_space(1))) const unsigned int guint;
typedef __attribute__((address_space(3))) unsigned int luint;
__device__ __forceinline__ void lds16(const void* g, void* l) {
    __builtin_amdgcn_global_load_lds((guint*)g, (luint*)l, 16, 0, 0);
}

// ---------------- adj (0/1 f32, 256 MB) -> bitmask (8 MB), streaming ----------
__global__ __launch_bounds__(256) void k_pack(const float* __restrict__ adj,
                                              unsigned int* __restrict__ mask) {
    int wid = blockIdx.x * 4 + (threadIdx.x >> 6);   // one wave per row
    int lane = threadIdx.x & 63;
    const float* row = adj + (size_t)wid * 8192 + lane;
    unsigned int* mrow = mask + wid * 256;
#pragma unroll 2
    for (int base = 0; base < 8192; base += 256) {
        float v0 = row[base];
        float v1 = row[base + 64];
        float v2 = row[base + 128];
        float v3 = row[base + 192];
        unsigned long long b0 = __ballot(v0 > 0.5f);
        unsigned long long b1 = __ballot(v1 > 0.5f);
        unsigned long long b2 = __ballot(v2 > 0.5f);
        unsigned long long b3 = __ballot(v3 > 0.5f);
        if (lane == 0) {
            *(ulonglong2*)(mrow + (base >> 5))     = make_ulonglong2(b0, b1);
            *(ulonglong2*)(mrow + (base >> 5) + 4) = make_ulonglong2(b2, b3);
        }
    }
}

// ---------------- kernel: W (512x256 f32) -> WT bf16 (256x512) ----------------
__global__ void k_cvt_wt(const float* __restrict__ W, unsigned short* __restrict__ wt) {
    int c = blockIdx.x;
    int t = threadIdx.x;
    wt[c * 512 + t]       = f2bf(W[(size_t)t * 256 + c]);
    wt[c * 512 + t + 256] = f2bf(W[(size_t)(t + 256) * 256 + c]);
}

// ------- h = input @ W (bf16 MFMA) fused with s1/s2 epilogue ------------------
// 512 blocks x 256 threads (4 waves, split-N: wave w owns cols w*64..w*64+63).
__global__ __launch_bounds__(256) void k_gemm_h(const float* __restrict__ input,
                                                const unsigned short* __restrict__ wt,
                                                const float* __restrict__ a,
                                                unsigned short* __restrict__ hbt,
                                                float* __restrict__ s1L,
                                                float* __restrict__ s2L) {
    __shared__ float red[2][4][16];
    int tid = threadIdx.x;
    int w = tid >> 6, lane = tid & 63, g = lane >> 4, r = lane & 15;
    int base = blockIdx.x * 16;

    f32x4 acc[4];
#pragma unroll
    for (int n = 0; n < 4; ++n) acc[n] = (f32x4)0.0f;

    const float* arow = input + (size_t)(base + r) * 512 + g * 8;
    const unsigned short* wp = wt + (size_t)(w * 64 + r) * 512 + g * 8;
#pragma unroll 4
    for (int kb = 0; kb < 512; kb += 32) {
        float4 a0 = *(const float4*)(arow + kb);
        float4 a1 = *(const float4*)(arow + kb + 4);
        short8 af;
        af[0] = (short)f2bf(a0.x); af[1] = (short)f2bf(a0.y);
        af[2] = (short)f2bf(a0.z); af[3] = (short)f2bf(a0.w);
        af[4] = (short)f2bf(a1.x); af[5] = (short)f2bf(a1.y);
        af[6] = (short)f2bf(a1.z); af[7] = (short)f2bf(a1.w);
#pragma unroll
        for (int n2 = 0; n2 < 4; ++n2) {
            short8 bf = *(const short8*)(wp + n2 * 8192 + kb);
            acc[n2] = __builtin_amdgcn_mfma_f32_16x16x32_bf16(af, bf, acc[n2], 0, 0, 0);
        }
    }
    int rowc = base + g * 4;
#pragma unroll
    for (int n2 = 0; n2 < 4; ++n2) {
        int col = w * 64 + n2 * 16 + r;
        ushort4 pk;
        pk.x = f2bf(acc[n2][0]); pk.y = f2bf(acc[n2][1]);
        pk.z = f2bf(acc[n2][2]); pk.w = f2bf(acc[n2][3]);
        *(ushort4*)(hbt + (size_t)col * 8192 + rowc) = pk;
    }
    float p1[4] = {0,0,0,0}, p2[4] = {0,0,0,0};
#pragma unroll
    for (int n2 = 0; n2 < 4; ++n2) {
        float a1v = a[w * 64 + n2 * 16 + r];
        float a2v = a[256 + w * 64 + n2 * 16 + r];
#pragma unroll
        for (int i = 0; i < 4; ++i) {
            p1[i] += acc[n2][i] * a1v;
            p2[i] += acc[n2][i] * a2v;
        }
    }
#pragma unroll
    for (int off = 8; off >= 1; off >>= 1) {
#pragma unroll
        for (int i = 0; i < 4; ++i) {
            p1[i] += __shfl_xor(p1[i], off);
            p2[i] += __shfl_xor(p2[i], off);
        }
    }
    if (r == 0) {
#pragma unroll
        for (int i = 0; i < 4; ++i) {
            red[0][w][g * 4 + i] = p1[i];
            red[1][w][g * 4 + i] = p2[i];
        }
    }
    __syncthreads();
    if (tid < 16) {
        float s1 = red[0][0][tid] + red[0][1][tid] + red[0][2][tid] + red[0][3][tid];
        float s2 = red[1][0][tid] + red[1][1][tid] + red[1][2][tid] + red[1][3][tid];
        s1L[base + tid] = s1 * L2E;
        s2L[base + tid] = s2 * L2E;
    }
}

// ---------------- main kernel: depth-2 pipelined masked-softmax PV ------------
// grid (128,4), 256 thr = 4 waves x 16 rows. 4 LDS bufs, 1 barrier/step,
// counted vmcnt(7); all inputs (mask/hbt/s2L) are L2/L3-resident.
__global__ __launch_bounds__(256, 2) void k_attn(const unsigned int* __restrict__ mask,
                                                 const unsigned short* __restrict__ hbt,
                                                 const float* __restrict__ s1L,
                                                 const float* __restrict__ s2L,
                                                 float* __restrict__ pS,
                                                 float* __restrict__ pZ) {
    __shared__ __align__(16) unsigned short tile[4][8192]; // 4 x (256 feat x 32 k) bf16

    int tid = threadIdx.x;
    int w = tid >> 6, lane = tid & 63, g = lane >> 4, r = lane & 15;
    int mb = blockIdx.x, chunk = blockIdx.y;
    int kc = chunk * 2048;
    int rowA = mb * 64 + w * 16 + r;
    float s1v = s1L[rowA];

    const unsigned int* mkp = mask + (size_t)rowA * 256 + chunk * 64;
    const float* svp = s2L + kc + g * 8;

    const unsigned short *hsrc0, *hsrc1, *hsrc2, *hsrc3;
    {
        int l2 = lane >> 2, sl = lane & 3;
        int r0 = 64 * w + l2,      ss0 = sl ^ ((r0 >> 1) & 3);
        int r1 = 64 * w + 16 + l2, ss1 = sl ^ ((r1 >> 1) & 3);
        int r2 = 64 * w + 32 + l2, ss2 = sl ^ ((r2 >> 1) & 3);
        int r3 = 64 * w + 48 + l2, ss3 = sl ^ ((r3 >> 1) & 3);
        hsrc0 = hbt + (size_t)r0 * 8192 + kc + ss0 * 8;
        hsrc1 = hbt + (size_t)r1 * 8192 + kc + ss1 * 8;
        hsrc2 = hbt + (size_t)r2 * 8192 + kc + ss2 * 8;
        hsrc3 = hbt + (size_t)r3 * 8192 + kc + ss3 * 8;
    }
    int sw = (r >> 1) & 3;
    int rdoff = r * 64 + ((g ^ sw) * 16);

    f32x4 acc[17];
#pragma unroll
    for (int n = 0; n < 17; ++n) acc[n] = (f32x4)0.0f;

    short8 onef;
    {
        short ov = (r == 0) ? (short)0x3F80 : (short)0;
#pragma unroll
        for (int j = 0; j < 8; ++j) onef[j] = ov;
    }

    unsigned int mkA, mkB, mkC, mkD;
    float4 svA0, svA1, svB0, svB1, svC0, svC1, svD0, svD1;

#define ISSUE(tt, bufn, MK, SV0, SV1) do {                                     \
        int t_ = (tt); if (t_ > 63) t_ = 63;                                   \
        int ko_ = t_ * 32;                                                     \
        char* lb_ = (char*)&tile[0][0] + (bufn) * 16384 + w * 4096;            \
        lds16(hsrc0 + ko_, lb_);                                               \
        lds16(hsrc1 + ko_, lb_ + 1024);                                        \
        lds16(hsrc2 + ko_, lb_ + 2048);                                        \
        lds16(hsrc3 + ko_, lb_ + 3072);                                        \
        MK = mkp[t_];                                                          \
        SV0 = *(const float4*)(svp + ko_);                                     \
        SV1 = *(const float4*)(svp + ko_ + 4);                                 \
    } while (0)

#define WAITBAR() do {                                                         \
        asm volatile("s_waitcnt vmcnt(7)" ::: "memory");                       \
        __builtin_amdgcn_sched_barrier(0);                                     \
        __builtin_amdgcn_s_barrier();                                          \
        __builtin_amdgcn_sched_barrier(0);                                     \
    } while (0)

#define COMPUTE(bufc, MK, SV0, SV1) do {                                       \
        unsigned int mby_ = (MK) >> (g * 8);                                   \
        short8 af_;                                                            \
        af_[0] = pw(mby_, 0, SV0.x, s1v);                                      \
        af_[1] = pw(mby_, 1, SV0.y, s1v);                                      \
        af_[2] = pw(mby_, 2, SV0.z, s1v);                                      \
        af_[3] = pw(mby_, 3, SV0.w, s1v);                                      \
        af_[4] = pw(mby_, 4, SV1.x, s1v);                                      \
        af_[5] = pw(mby_, 5, SV1.y, s1v);                                      \
        af_[6] = pw(mby_, 6, SV1.z, s1v);                                      \
        af_[7] = pw(mby_, 7, SV1.w, s1v);                                      \
        const char* tb_ = (const char*)&tile[0][0] + (bufc) * 16384 + rdoff;   \
        _Pragma("unroll")                                                      \
        for (int n_ = 0; n_ < 16; ++n_) {                                      \
            short8 bf_ = *(const short8*)(tb_ + n_ * 1024);                    \
            acc[n_] = __builtin_amdgcn_mfma_f32_16x16x32_bf16(af_, bf_, acc[n_], 0, 0, 0); \
        }                                                                      \
        acc[16] = __builtin_amdgcn_mfma_f32_16x16x32_bf16(af_, onef, acc[16], 0, 0, 0);    \
    } while (0)

    // prologue: two steps in flight
    ISSUE(0, 0, mkA, svA0, svA1);
    ISSUE(1, 1, mkB, svB0, svB1);

    for (int s = 0; s < 64; s += 4) {
        WAITBAR();
        ISSUE(s + 2, 2, mkC, svC0, svC1);
        COMPUTE(0, mkA, svA0, svA1);
        WAITBAR();
        ISSUE(s + 3, 3, mkD, svD0, svD1);
        COMPUTE(1, mkB, svB0, svB1);
        WAITBAR();
        ISSUE(s + 4, 0, mkA, svA0, svA1);
        COMPUTE(2, mkC, svC0, svC1);
        WAITBAR();
        ISSUE(s + 5, 1, mkB, svB0, svB1);
        COMPUTE(3, mkD, svD0, svD1);
    }

    // epilogue: write partial S and Z
    float* ps = pS + ((size_t)chunk << 21);
    int rowc = mb * 64 + w * 16 + g * 4;
#pragma unroll
    for (int n = 0; n < 16; ++n) {
#pragma unroll
        for (int i = 0; i < 4; ++i)
            ps[(size_t)(rowc + i) * 256 + n * 16 + r] = acc[n][i];
    }
    if (r == 0) {
        float* pz = pZ + chunk * 8192 + rowc;
#pragma unroll
        for (int i = 0; i < 4; ++i) pz[i] = acc[16][i];
    }
#undef ISSUE
#undef WAITBAR
#undef COMPUTE
}

// ---------------- final: reduce partials, divide, mish ------------------------
__global__ void k_final(const float* __restrict__ pS, const float* __restrict__ pZ,
                        float* __restrict__ out) {
    int i = blockIdx.x;
    int f = threadIdx.x;
    size_t o = (size_t)i * 256 + f;
    float sv = pS[o] + pS[o + (1u << 21)] + pS[o + (2u << 21)] + pS[o + (3u << 21)];
    float z = pZ[i] + pZ[i + 8192] + pZ[i + 16384] + pZ[i + 24576];
    float hp = sv / z;
    out[o] = mishf(hp);
}

extern "C" void kernel_launch(void* const* d_in, const int* in_sizes, int n_in,
                              void* d_out, int out_size, void* d_ws, size_t ws_size,
                              hipStream_t stream) {
    const float* input = (const float*)d_in[0];
    const float* adj   = (const float*)d_in[1];
    const float* W     = (const float*)d_in[2];
    const float* a     = (const float*)d_in[3];
    float* out = (float*)d_out;

    char* ws = (char*)d_ws;
    unsigned short* wt   = (unsigned short*)ws;                // 256 KB
    unsigned short* hbt  = (unsigned short*)(ws + 262144);     // 4 MB
    float* s1L           = (float*)(ws + 4456448);             // 32 KB
    float* s2L           = (float*)(ws + 4489216);             // 32 KB
    unsigned int* mask   = (unsigned int*)(ws + 4521984);      // 8 MB
    float* pS            = (float*)(ws + 12910592);            // 32 MB
    float* pZ            = (float*)(ws + 46465024);            // 128 KB (end ~46.6 MB)

    hipLaunchKernelGGL(k_pack, dim3(2048), dim3(256), 0, stream, adj, mask);
    hipLaunchKernelGGL(k_cvt_wt, dim3(256), dim3(256), 0, stream, W, wt);
    hipLaunchKernelGGL(k_gemm_h, dim3(512), dim3(256), 0, stream, input, wt, a, hbt, s1L, s2L);
    hipLaunchKernelGGL(k_attn, dim3(128, 4), dim3(256), 0, stream, mask, hbt, s1L, s2L, pS, pZ);
    hipLaunchKernelGGL(k_final, dim3(8192), dim3(256), 0, stream, pS, pZ, out);
}